// Round 2
// baseline (744.677 us; speedup 1.0000x reference)
//
#include <hip/hip_runtime.h>

typedef __attribute__((ext_vector_type(8))) short short8;
typedef __attribute__((ext_vector_type(4))) float floatx4;

__device__ __forceinline__ float bf2f(unsigned short u) {
    return __uint_as_float(((unsigned int)u) << 16);
}
__device__ __forceinline__ unsigned short f2bf(float f) {
    unsigned int x = __float_as_uint(f);
    unsigned int r = (x + 0x7FFFu + ((x >> 16) & 1u)) >> 16;
    return (unsigned short)r;
}
// generic load: input arrays may be fp32 or bf16; flag detected from N (==1.0f).
__device__ __forceinline__ float ldf(const void* p, long i, bool f32) {
    return f32 ? ((const float*)p)[i] : bf2f(((const unsigned short*)p)[i]);
}
__device__ __forceinline__ bool detect_f32(const unsigned short* Nv) {
    // N == 1.0: bf16 -> halfword0 = 0x3F80 ; fp32 -> halfword0 = 0x0000
    return Nv[0] == 0;
}

// params block layout (floats)
#define P_WIH 0
#define P_WHH 3072
#define P_BIH 6144
#define P_BHH 6240
#define P_WR1 6336
#define P_BR1 6676
#define P_WR2 6686
#define P_BR2 6754
#define P_I   6756
#define P_R   6788
#define P_S   6820
#define P_IT  6852
#define P_RT  6884
#define P_N   6916
#define P_HX0 6917
#define P_TOT 6949

// ---------------------------------------------------------------------------
// Prologue: normalize small tensors to fp32 P-block; build combined GEMM
// weights WbT1 (144 x 128 bf16: 128 z-cols + 4 el + 4 er + 8 zero) and
// WbT2 (48 x 128 bf16: 32 z-cols + el + er + 14 zero), el/er = W @ a halves.
// ---------------------------------------------------------------------------
__global__ __launch_bounds__(256) void norm_params(
    const void* W1, const void* a1, const void* W2, const void* a2,
    const void* W_ih, const void* W_hh, const void* b_ih, const void* b_hh,
    const void* Wr1, const void* br1, const void* Wr2, const void* br2,
    const void* Iv, const void* Rv, const void* Sv, const void* Itv, const void* Rtv,
    const void* Nv, const void* hx0,
    float* __restrict__ P, unsigned short* __restrict__ WbT1,
    unsigned short* __restrict__ WbT2)
{
    bool f32 = detect_f32((const unsigned short*)Nv);
    int tid = threadIdx.x;
    struct Item { const void* p; int n; int off; };
    const Item items[15] = {
        {W_ih, 3072, P_WIH}, {W_hh, 3072, P_WHH}, {b_ih, 96, P_BIH}, {b_hh, 96, P_BHH},
        {Wr1, 340, P_WR1}, {br1, 10, P_BR1}, {Wr2, 68, P_WR2}, {br2, 2, P_BR2},
        {Iv, 32, P_I}, {Rv, 32, P_R}, {Sv, 32, P_S}, {Itv, 32, P_IT}, {Rtv, 32, P_RT},
        {Nv, 1, P_N}, {hx0, 32, P_HX0}
    };
    for (int it = 0; it < 15; it++)
        for (int i = tid; i < items[it].n; i += 256)
            P[items[it].off + i] = ldf(items[it].p, i, f32);

    // WbT1: col-major-by-col [col][k], k in [0,128)
    for (int idx = tid; idx < 144 * 128; idx += 256) {
        int col = idx >> 7, k = idx & 127;
        float v = 0.f;
        if (col < 128) {
            int h = col >> 5, e = col & 31;
            v = ldf(W1, (h * 128 + k) * 32 + e, f32);
        } else if (col < 136) {
            int q = col - 128;
            int h = (q < 4) ? q : q - 4;
            int off = (q < 4) ? 0 : 32;
            float s = 0.f;
            for (int e = 0; e < 32; e++)
                s += ldf(W1, (h * 128 + k) * 32 + e, f32) * ldf(a1, h * 64 + off + e, f32);
            v = s;
        }
        WbT1[col * 128 + k] = f2bf(v);
    }
    // WbT2
    for (int idx = tid; idx < 48 * 128; idx += 256) {
        int col = idx >> 7, k = idx & 127;
        float v = 0.f;
        if (col < 32) {
            v = ldf(W2, k * 32 + col, f32);
        } else if (col < 34) {
            int off = (col == 32) ? 0 : 32;
            float s = 0.f;
            for (int e = 0; e < 32; e++)
                s += ldf(W2, k * 32 + e, f32) * ldf(a2, off + e, f32);
            v = s;
        }
        WbT2[col * 128 + k] = f2bf(v);
    }
}

// ---------------------------------------------------------------------------
// K1/K3: C[M x NT*16] = X[M x 128] @ WbT^T via MFMA 16x16x32 bf16.
// cols [0,HC*32) -> Z (bf16), [HC*32,HC*32+HC) -> EL (f32), next HC -> ER.
// DYN: X may be fp32 or bf16 (flag from Nv). row0 = global row offset of chunk.
// ---------------------------------------------------------------------------
template<int NT, int HC, bool DYN>
__global__ __launch_bounds__(256) void gat_linear(
    const void* __restrict__ Xv, const unsigned short* __restrict__ WbT,
    unsigned short* __restrict__ Z, float* __restrict__ EL, float* __restrict__ ER,
    const unsigned short* __restrict__ Nv, long row0)
{
    constexpr int NCOL = NT * 16;
    constexpr int LDW  = 136;
    __shared__ unsigned short Ws[NCOL * LDW];
    int tid = threadIdx.x;
    // stage WbT -> LDS (padded), 16B chunks
    for (int idx = tid; idx < NCOL * 16; idx += 256) {
        int col = idx >> 4, ch = idx & 15;
        *(uint4*)(&Ws[col * LDW + ch * 8]) = *(const uint4*)(&WbT[col * 128 + ch * 8]);
    }
    __syncthreads();

    bool f32 = DYN ? detect_f32(Nv) : false;
    int wave = tid >> 6, lane = tid & 63;
    int l15 = lane & 15, quad = lane >> 4;
    long lrow = (long)blockIdx.x * 64 + wave * 16;   // chunk-local row base

    floatx4 acc[NT];
    floatx4 zz = {0.f, 0.f, 0.f, 0.f};
    #pragma unroll
    for (int i = 0; i < NT; i++) acc[i] = zz;

    long xoff = (row0 + lrow + l15) * 128 + quad * 8;
    #pragma unroll
    for (int kt = 0; kt < 4; kt++) {
        short8 afrag;
        if (DYN && f32) {
            const float* xr = (const float*)Xv + xoff + kt * 32;
            float4 u0 = ((const float4*)xr)[0];
            float4 u1 = ((const float4*)xr)[1];
            union { short8 v; unsigned short u[8]; } af;
            af.u[0] = f2bf(u0.x); af.u[1] = f2bf(u0.y);
            af.u[2] = f2bf(u0.z); af.u[3] = f2bf(u0.w);
            af.u[4] = f2bf(u1.x); af.u[5] = f2bf(u1.y);
            af.u[6] = f2bf(u1.z); af.u[7] = f2bf(u1.w);
            afrag = af.v;
        } else {
            afrag = *(const short8*)((const unsigned short*)Xv + xoff + kt * 32);
        }
        #pragma unroll
        for (int nt = 0; nt < NT; nt++) {
            short8 bfrag = *(const short8*)(&Ws[(nt * 16 + l15) * LDW + kt * 32 + quad * 8]);
            acc[nt] = __builtin_amdgcn_mfma_f32_16x16x32_bf16(afrag, bfrag, acc[nt], 0, 0, 0);
        }
    }

    #pragma unroll
    for (int nt = 0; nt < NT; nt++) {
        int col = nt * 16 + l15;
        #pragma unroll
        for (int r = 0; r < 4; r++) {
            long grow = lrow + quad * 4 + r;          // chunk-local
            float v = acc[nt][r];
            if (col < HC * 32) {
                Z[grow * (HC * 32) + col] = f2bf(v);
            } else if (col < HC * 32 + HC) {
                EL[grow * HC + (col - HC * 32)] = v;
            } else if (col < HC * 32 + 2 * HC) {
                ER[grow * HC + (col - HC * 32 - HC)] = v;
            }
        }
    }
}

// ---------------------------------------------------------------------------
// K2: GAT1 aggregation. One wave per (t,n), t chunk-local.
// ---------------------------------------------------------------------------
__global__ __launch_bounds__(256) void gat1_aggr(
    const int* __restrict__ src,
    const unsigned short* __restrict__ Z,   // (TC*10000) x 128 bf16
    const float* __restrict__ EL,           // (TC*10000) x 4
    const float* __restrict__ ER,
    unsigned short* __restrict__ H1)        // (TC*10000) x 128 bf16
{
    __shared__ float alpha_s[4][4][32];
    __shared__ int   src_s[4][32];
    int tid = threadIdx.x;
    int w = tid >> 6, lane = tid & 63;
    int t = blockIdx.y;
    int n = blockIdx.x * 4 + w;
    long base = (long)t * 10000 + n;

    int d = lane & 31, g = lane >> 5;
    int sidx = src[n * 32 + d];
    long sbase = (long)t * 10000 + sidx;
    float2 el = *(const float2*)(EL + sbase * 4 + g * 2);
    float2 er = *(const float2*)(ER + base * 4 + g * 2);
    float e0 = el.x + er.x, e1 = el.y + er.y;
    e0 = e0 >= 0.f ? e0 : 0.01f * e0;
    e1 = e1 >= 0.f ? e1 : 0.01f * e1;
    float m0 = e0, m1 = e1;
    for (int off = 16; off > 0; off >>= 1) {
        m0 = fmaxf(m0, __shfl_xor(m0, off));
        m1 = fmaxf(m1, __shfl_xor(m1, off));
    }
    float x0 = __expf(e0 - m0), x1 = __expf(e1 - m1);
    float s0 = x0, s1 = x1;
    for (int off = 16; off > 0; off >>= 1) {
        s0 += __shfl_xor(s0, off);
        s1 += __shfl_xor(s1, off);
    }
    alpha_s[w][2 * g + 0][d] = x0 / s0;
    alpha_s[w][2 * g + 1][d] = x1 / s1;
    if (g == 0) src_s[w][d] = sidx;
    __syncthreads();

    int h = lane >> 4;
    const float* al = alpha_s[w][h];
    float a0 = 0.f, a1 = 0.f;
    #pragma unroll
    for (int dd = 0; dd < 32; dd++) {
        int mm = src_s[w][dd];
        long zb = ((long)t * 10000 + mm) * 128 + lane * 2;
        unsigned int u = *(const unsigned int*)(Z + zb);
        float zv0 = bf2f((unsigned short)u);
        float zv1 = bf2f((unsigned short)(u >> 16));
        float av = al[dd];
        a0 += av * zv0;
        a1 += av * zv1;
    }
    a0 = fmaxf(a0, 0.f);
    a1 = fmaxf(a1, 0.f);
    unsigned int o = (unsigned int)f2bf(a0) | ((unsigned int)f2bf(a1) << 16);
    *(unsigned int*)(H1 + base * 128 + lane * 2) = o;
}

// ---------------------------------------------------------------------------
// K4: GAT2 aggregation + relu + global max pool into cur[t0+t][32].
// ---------------------------------------------------------------------------
__global__ __launch_bounds__(256) void gat2_aggr(
    const int* __restrict__ src,
    const unsigned short* __restrict__ Z2,  // (TC*10000) x 32 bf16
    const float* __restrict__ EL2,          // (TC*10000)
    const float* __restrict__ ER2,
    int* __restrict__ cur, int t0)
{
    __shared__ int bm[32];
    int tid = threadIdx.x, w = tid >> 6, lane = tid & 63;
    int t = blockIdx.y;
    int e = lane & 31, g = lane >> 5;
    if (tid < 32) bm[tid] = 0;
    __syncthreads();
    for (int it = 0; it < 8; it++) {
        int n = blockIdx.x * 32 + w * 8 + it;
        if (n < 10000) {
            int sidx = src[n * 32 + e];
            long sb = (long)t * 10000 + sidx;
            float ev = EL2[sb] + ER2[(long)t * 10000 + n];
            ev = ev >= 0.f ? ev : 0.01f * ev;
            float m = ev;
            for (int off = 16; off > 0; off >>= 1) m = fmaxf(m, __shfl_xor(m, off));
            float x = __expf(ev - m);
            float s = x;
            for (int off = 16; off > 0; off >>= 1) s += __shfl_xor(s, off);
            float alpha = x / s;
            float acc = 0.f;
            #pragma unroll
            for (int i = 0; i < 16; i++) {
                int dd = g * 16 + i;
                float av = __shfl(alpha, dd);
                int mm = src[n * 32 + dd];
                float zv = bf2f(Z2[((long)t * 10000 + mm) * 32 + e]);
                acc += av * zv;
            }
            acc += __shfl_xor(acc, 32);
            float outv = fmaxf(acc, 0.f);
            if (g == 0) atomicMax(&bm[e], __float_as_int(outv));
        }
    }
    __syncthreads();
    if (tid < 32) atomicMax(&cur[(t0 + t) * 32 + tid], bm[tid]);
}

// ---------------------------------------------------------------------------
// K5: GRU + readout + SIR physics. fp32 params from P-block. Output dtype
// branched on detected flag.
// ---------------------------------------------------------------------------
__global__ __launch_bounds__(128) void gru_head(
    const float* __restrict__ P, const float* __restrict__ cur,
    void* __restrict__ outv, const unsigned short* __restrict__ Nv)
{
    bool f32 = detect_f32(Nv);
    __shared__ float Wih[96 * 32], Whh[96 * 32];
    __shared__ float hx[32], gi[96], gh[96], nh[34], curt[32];
    int tid = threadIdx.x;
    for (int i = tid; i < 96 * 32; i += 128) {
        Wih[i] = P[P_WIH + i];
        Whh[i] = P[P_WHH + i];
    }
    if (tid < 32) hx[tid] = P[P_HX0 + tid];
    __syncthreads();

    for (int t = 0; t < 32; t++) {
        if (tid < 32) curt[tid] = cur[t * 32 + tid];
        __syncthreads();
        if (tid < 96) {
            float si = 0.f, sh = 0.f;
            for (int k = 0; k < 32; k++) {
                si += curt[k] * Wih[tid * 32 + k];
                sh += hx[k] * Whh[tid * 32 + k];
            }
            gi[tid] = si + P[P_BIH + tid];
            gh[tid] = sh + P[P_BHH + tid];
        }
        __syncthreads();
        if (tid < 32) {
            float r  = 1.f / (1.f + __expf(-(gi[tid] + gh[tid])));
            float zg = 1.f / (1.f + __expf(-(gi[32 + tid] + gh[32 + tid])));
            float ng = tanhf(gi[64 + tid] + r * gh[64 + tid]);
            float hv = (1.f - zg) * ng + zg * hx[tid];
            hx[tid] = hv;
            nh[tid] = hv;
            if (tid == 0) { nh[32] = P[P_IT + t]; nh[33] = P[P_RT + t]; }
        }
        __syncthreads();
        if (tid < 10) {
            float s = P[P_BR1 + tid];
            for (int k = 0; k < 34; k++) s += nh[k] * P[P_WR1 + tid * 34 + k];
            int i = tid >> 1;
            int oi = ((tid & 1) == 0) ? (t * 5 + i) : (160 + t * 5 + i);
            if (f32) ((float*)outv)[oi] = s;
            else     ((unsigned short*)outv)[oi] = f2bf(s);
        }
        if (tid == 64) {
            float ab0 = P[P_BR2 + 0], ab1 = P[P_BR2 + 1];
            for (int k = 0; k < 34; k++) {
                ab0 += nh[k] * P[P_WR2 + k];
                ab1 += nh[k] * P[P_WR2 + 34 + k];
            }
            float a_s = 1.f / (1.f + __expf(-ab0));
            float b_s = 1.f / (1.f + __expf(-ab1));
            float Ns = P[P_N];
            float lI = P[P_I + t], lR = P[P_R + t], lS = P[P_S + t];
            float dI = 0.f, dR = 0.f;
            for (int i = 0; i < 5; i++) {
                if (i > 0) { lI += dI; lR += dR; lS = Ns - lI - lR; }
                dI = a_s * lI * (lS / Ns) - b_s * lI;
                dR = b_s * lI;
                if (f32) {
                    ((float*)outv)[320 + t * 5 + i] = dI;
                    ((float*)outv)[480 + t * 5 + i] = dR;
                } else {
                    ((unsigned short*)outv)[320 + t * 5 + i] = f2bf(dI);
                    ((unsigned short*)outv)[480 + t * 5 + i] = f2bf(dR);
                }
            }
        }
        __syncthreads();
    }
}

extern "C" void kernel_launch(void* const* d_in, const int* in_sizes, int n_in,
                              void* d_out, int out_size, void* d_ws, size_t ws_size,
                              hipStream_t stream) {
    const void* h    = d_in[0];
    const int*  src  = (const int*)d_in[1];
    const void* Nv   = d_in[2];
    const void* Iv   = d_in[3];
    const void* Rv   = d_in[4];
    const void* Sv   = d_in[5];
    const void* Itv  = d_in[6];
    const void* Rtv  = d_in[7];
    const void* hx0  = d_in[8];
    const void* W1   = d_in[9];
    const void* a1   = d_in[10];
    const void* W2   = d_in[11];
    const void* a2   = d_in[12];
    const void* W_ih = d_in[13];
    const void* W_hh = d_in[14];
    const void* b_ih = d_in[15];
    const void* b_hh = d_in[16];
    const void* Wr1  = d_in[17];
    const void* br1  = d_in[18];
    const void* Wr2  = d_in[19];
    const void* br2  = d_in[20];
    const unsigned short* Nu = (const unsigned short*)Nv;

    // pick chunk size TC in {32,16,8,4} (keeps rows/64 exact) to fit ws_size
    int TC = 4;
    for (int c = 32; c >= 4; c >>= 1) {
        size_t need = (size_t)c * 10000 * (128 * 2 + 128 * 2 + 16 + 16) + (1 << 20);
        if (need <= ws_size) { TC = c; break; }
    }
    long CR = (long)TC * 10000;   // rows per chunk

    char* ws = (char*)d_ws;
    size_t off = 0;
    auto alloc = [&](size_t b) {
        void* p = ws + off;
        off += (b + 255) & ~(size_t)255;
        return p;
    };
    float*          Pb   = (float*)alloc(P_TOT * 4);
    unsigned short* WbT1 = (unsigned short*)alloc(144 * 128 * 2);
    unsigned short* WbT2 = (unsigned short*)alloc(48 * 128 * 2);
    float*          cur  = (float*)alloc(32 * 32 * 4);
    unsigned short* z1   = (unsigned short*)alloc((size_t)CR * 128 * 2);
    unsigned short* h1   = (unsigned short*)alloc((size_t)CR * 128 * 2);
    float*          el1  = (float*)alloc((size_t)CR * 4 * 4);
    float*          er1  = (float*)alloc((size_t)CR * 4 * 4);
    unsigned short* z2   = z1;    // dead after gat1_aggr
    float*          el2  = el1;
    float*          er2  = er1;

    hipMemsetAsync(cur, 0, 32 * 32 * 4, stream);
    norm_params<<<1, 256, 0, stream>>>(W1, a1, W2, a2, W_ih, W_hh, b_ih, b_hh,
                                       Wr1, br1, Wr2, br2, Iv, Rv, Sv, Itv, Rtv,
                                       Nv, hx0, Pb, WbT1, WbT2);
    int nchunks = 32 / TC;
    int g1 = (int)(CR / 64);      // CR divisible by 64 since TC%4==0
    for (int c = 0; c < nchunks; c++) {
        long row0 = (long)c * CR;
        gat_linear<9, 4, true><<<g1, 256, 0, stream>>>(h, WbT1, z1, el1, er1, Nu, row0);
        gat1_aggr<<<dim3(2500, TC), 256, 0, stream>>>(src, z1, el1, er1, h1);
        gat_linear<3, 1, false><<<g1, 256, 0, stream>>>(h1, WbT2, z2, el2, er2, Nu, 0);
        gat2_aggr<<<dim3(313, TC), 256, 0, stream>>>(src, z2, el2, er2, (int*)cur, c * TC);
    }
    gru_head<<<1, 128, 0, stream>>>(Pb, cur, d_out, Nu);
}